// Round 1
// baseline (4845.626 us; speedup 1.0000x reference)
//
#include <hip/hip_runtime.h>
#include <hip/hip_bf16.h>

#define G1 __attribute__((address_space(1)))
#define L3 __attribute__((address_space(3)))

typedef __bf16 bf16x8 __attribute__((ext_vector_type(8)));
typedef float f32x4 __attribute__((ext_vector_type(4)));

__device__ __forceinline__ ushort f2bf(float f) {
  union { float f; uint u; } v; v.f = f;
  uint u = v.u;
  u += 0x7fffu + ((u >> 16) & 1u);   // RNE
  return (ushort)(u >> 16);
}

// ---------------- cast fp32 -> bf16 ----------------
__global__ void cast_bf16_kernel(const float* __restrict__ in, ushort* __restrict__ out, int n4) {
  int i = blockIdx.x * 256 + threadIdx.x;
  if (i >= n4) return;
  float4 v = ((const float4*)in)[i];
  ushort4 o;
  o.x = f2bf(v.x); o.y = f2bf(v.y); o.z = f2bf(v.z); o.w = f2bf(v.w);
  ((ushort4*)out)[i] = o;
}

// ---------------- bt-GEMM: out[m][n] = sum_k A[m][k]*B[n][k] + bias[n] ----------------
// mode 0: out bf16 at [(b*16+h)*2048+t][dd]  (Q/K layout, m=b*2048+t, n=h*128+dd)
// mode 1: out bf16 at [(b*16+h)*128+dd][t]   (V transposed)
// mode 2: out fp32 row-major [m][n]
__global__ __launch_bounds__(256, 2)
void gemm_bt(const ushort* __restrict__ A, const ushort* __restrict__ Bm,
             const float* __restrict__ bias, void* __restrict__ outp,
             int mode, int M, int N, int K) {
  __shared__ ushort As[128 * 32];
  __shared__ ushort Bs[128 * 32];
  const int tid  = threadIdx.x;
  const int wave = tid >> 6, lane = tid & 63;
  const int l15  = lane & 15, quad = lane >> 4;
  const int m0 = blockIdx.x * 128, n0 = blockIdx.y * 128;
  const int wm = (wave & 1) * 64, wn = (wave >> 1) * 64;

  f32x4 acc[4][4] = {};
  for (int k0 = 0; k0 < K; k0 += 32) {
    __syncthreads();
    for (int i = 0; i < 2; ++i) {
      int c = (wave * 2 + i) * 64 + lane;     // 16B chunk id, 0..511
      int row = c >> 2, cib = c & 3;
      const ushort* ga = A  + (size_t)(m0 + row) * K + k0 + cib * 8;
      const ushort* gb = Bm + (size_t)(n0 + row) * K + k0 + cib * 8;
      __builtin_amdgcn_global_load_lds((G1 uint*)ga, (L3 uint*)&As[c * 8], 16, 0, 0);
      __builtin_amdgcn_global_load_lds((G1 uint*)gb, (L3 uint*)&Bs[c * 8], 16, 0, 0);
    }
    __syncthreads();
    bf16x8 af[4], bfr[4];
    for (int mi = 0; mi < 4; ++mi)
      af[mi]  = *(const bf16x8*)&As[(wm + mi * 16 + l15) * 32 + quad * 8];
    for (int ni = 0; ni < 4; ++ni)
      bfr[ni] = *(const bf16x8*)&Bs[(wn + ni * 16 + l15) * 32 + quad * 8];
    for (int ni = 0; ni < 4; ++ni)
      for (int mi = 0; mi < 4; ++mi)
        acc[mi][ni] = __builtin_amdgcn_mfma_f32_16x16x32_bf16(af[mi], bfr[ni], acc[mi][ni], 0, 0, 0);
  }

  for (int mi = 0; mi < 4; ++mi)
    for (int ni = 0; ni < 4; ++ni) {
      int n = n0 + wn + ni * 16 + l15;
      float bv = bias[n];
      for (int r = 0; r < 4; ++r) {
        int m = m0 + wm + mi * 16 + quad * 4 + r;   // C/D: row = quad*4+reg, col = l15 (m89/m91)
        float v = acc[mi][ni][r] + bv;
        if (mode == 0) {
          int b = m >> 11, t = m & 2047, h = n >> 7, dd = n & 127;
          ((ushort*)outp)[(((size_t)(b * 16 + h) * 2048 + t) << 7) + dd] = f2bf(v);
        } else if (mode == 1) {
          int b = m >> 11, t = m & 2047, h = n >> 7, dd = n & 127;
          ((ushort*)outp)[(((size_t)(b * 16 + h) * 128 + dd) << 11) + t] = f2bf(v);
        } else {
          ((float*)outp)[(size_t)m * N + n] = v;
        }
      }
    }
}

// ---------------- flash attention: Q,K (bh,t,d) bf16; Vt (bh,d,t) bf16; Y (b,t,C) bf16 ----------------
__global__ __launch_bounds__(256, 2)
void attn_kernel(const ushort* __restrict__ Q, const ushort* __restrict__ Kh,
                 const ushort* __restrict__ Vt, const float* __restrict__ mask,
                 ushort* __restrict__ Y) {
  __shared__ ushort Ks[64 * 128];    // K-tile, rows=t (64), cols=d (128), no pad (global_load_lds)
  __shared__ ushort Vs[128 * 72];    // Vt-tile, rows=d (128), cols=t (64), stride 72 (16B-aligned pad)
  __shared__ ushort Ps[4 * 32 * 64]; // per-wave P (32 q-rows x 64 k-cols)
  const int tid  = threadIdx.x;
  const int wave = tid >> 6, lane = tid & 63;
  const int l15  = lane & 15, quad = lane >> 4;
  const int qt = blockIdx.x, bh = blockIdx.y;
  const int b  = bh >> 4;
  const int qw0 = qt * 128 + wave * 32;
  const ushort* Qb = Q  + (size_t)bh * 2048 * 128;
  const ushort* Kb = Kh + (size_t)bh * 2048 * 128;
  const ushort* Vb = Vt + (size_t)bh * 128 * 2048;
  const float*  mrow = mask + b * 2048;

  bf16x8 aq[2][4];   // Q A-frags: A[m=l15][k=quad*8+j], dk covers d=128
  for (int m2 = 0; m2 < 2; ++m2)
    for (int dk = 0; dk < 4; ++dk)
      aq[m2][dk] = *(const bf16x8*)(Qb + (size_t)(qw0 + m2 * 16 + l15) * 128 + dk * 32 + quad * 8);

  float mi_[2][4], li[2][4];
  f32x4 O[2][8] = {};
  for (int m2 = 0; m2 < 2; ++m2)
    for (int r = 0; r < 4; ++r) { mi_[m2][r] = -3.0e38f; li[m2][r] = 0.f; }

  const float scale = 0.08838834764831845f;  // 1/sqrt(128)
  const int nkt = 2 * qt + 2;
  for (int it = 0; it < nkt; ++it) {
    const int k0 = it * 64;
    __syncthreads();
    // stage K tile: 16KB globally contiguous
    for (int i = 0; i < 4; ++i) {
      int c = (wave * 4 + i) * 64 + lane;
      __builtin_amdgcn_global_load_lds((G1 uint*)(Kb + (size_t)k0 * 128 + c * 8),
                                       (L3 uint*)&Ks[c * 8], 16, 0, 0);
    }
    // stage Vt tile via VGPRs (padded LDS rows)
    uint4 vv[4]; int dvi[4], cki[4];
    for (int i = 0; i < 4; ++i) {
      int idx = i * 256 + tid;
      int d = idx >> 3, ck = idx & 7;
      vv[i] = *(const uint4*)(Vb + (size_t)d * 2048 + k0 + ck * 8);
      dvi[i] = d; cki[i] = ck;
    }
    for (int i = 0; i < 4; ++i)
      *(uint4*)&Vs[dvi[i] * 72 + cki[i] * 8] = vv[i];
    __syncthreads();

    if (k0 <= qw0 + 31) {    // tile intersects this wave's causal range
      float mk[4];
      for (int ns = 0; ns < 4; ++ns) mk[ns] = mrow[k0 + ns * 16 + l15];

      f32x4 s[2][4] = {};
      for (int ns = 0; ns < 4; ++ns) {
        bf16x8 kb[4];
        for (int dk = 0; dk < 4; ++dk)
          kb[dk] = *(const bf16x8*)&Ks[(ns * 16 + l15) * 128 + dk * 32 + quad * 8];
        for (int m2 = 0; m2 < 2; ++m2)
          for (int dk = 0; dk < 4; ++dk)
            s[m2][ns] = __builtin_amdgcn_mfma_f32_16x16x32_bf16(aq[m2][dk], kb[dk], s[m2][ns], 0, 0, 0);
      }

      for (int m2 = 0; m2 < 2; ++m2) {
        for (int ns = 0; ns < 4; ++ns) {
          int kc = k0 + ns * 16 + l15;
          for (int r = 0; r < 4; ++r) {
            int qr = qw0 + m2 * 16 + quad * 4 + r;
            float v = s[m2][ns][r] * scale + mk[ns];
            s[m2][ns][r] = (kc > qr) ? -3.0e38f : v;
          }
        }
        for (int r = 0; r < 4; ++r) {
          float rm = fmaxf(fmaxf(s[m2][0][r], s[m2][1][r]), fmaxf(s[m2][2][r], s[m2][3][r]));
          rm = fmaxf(rm, __shfl_xor(rm, 1));
          rm = fmaxf(rm, __shfl_xor(rm, 2));
          rm = fmaxf(rm, __shfl_xor(rm, 4));
          rm = fmaxf(rm, __shfl_xor(rm, 8));
          float mold = mi_[m2][r];
          float mnew = fmaxf(mold, rm);
          float al = __expf(mold - mnew);
          float rs = 0.f;
          for (int ns = 0; ns < 4; ++ns) {
            float p = __expf(s[m2][ns][r] - mnew);
            rs += p;
            Ps[wave * 2048 + (m2 * 16 + quad * 4 + r) * 64 + ns * 16 + l15] = f2bf(p);
          }
          rs += __shfl_xor(rs, 1);
          rs += __shfl_xor(rs, 2);
          rs += __shfl_xor(rs, 4);
          rs += __shfl_xor(rs, 8);
          li[m2][r] = li[m2][r] * al + rs;
          mi_[m2][r] = mnew;
          for (int dd = 0; dd < 8; ++dd) O[m2][dd][r] *= al;
        }
      }
      // PV: P (A-layout from LDS) x Vt (B[k][n] = Vs[n][k], contiguous along k)
      for (int kk = 0; kk < 2; ++kk) {
        bf16x8 pa[2];
        for (int m2 = 0; m2 < 2; ++m2)
          pa[m2] = *(const bf16x8*)&Ps[wave * 2048 + (m2 * 16 + l15) * 64 + kk * 32 + quad * 8];
        for (int dd = 0; dd < 8; ++dd) {
          bf16x8 vbf = *(const bf16x8*)&Vs[(dd * 16 + l15) * 72 + kk * 32 + quad * 8];
          for (int m2 = 0; m2 < 2; ++m2)
            O[m2][dd] = __builtin_amdgcn_mfma_f32_16x16x32_bf16(pa[m2], vbf, O[m2][dd], 0, 0, 0);
        }
      }
    }
  }

  for (int m2 = 0; m2 < 2; ++m2)
    for (int dd = 0; dd < 8; ++dd)
      for (int r = 0; r < 4; ++r) {
        float v = O[m2][dd][r] / li[m2][r];
        int t = qw0 + m2 * 16 + quad * 4 + r;
        Y[((size_t)(b * 2048 + t)) * 2048 + (bh & 15) * 128 + dd * 16 + l15] = f2bf(v);
      }
}

extern "C" void kernel_launch(void* const* d_in, const int* in_sizes, int n_in,
                              void* d_out, int out_size, void* d_ws, size_t ws_size,
                              hipStream_t stream) {
  const float* x     = (const float*)d_in[0];
  const float* amask = (const float*)d_in[1];
  const float* Wq = (const float*)d_in[2];
  const float* bq = (const float*)d_in[3];
  const float* Wk = (const float*)d_in[4];
  const float* bk = (const float*)d_in[5];
  const float* Wv = (const float*)d_in[6];
  const float* bv = (const float*)d_in[7];
  const float* Wp = (const float*)d_in[8];
  const float* bp = (const float*)d_in[9];

  char* ws = (char*)d_ws;
  ushort* xb  = (ushort*)(ws);                  // 8192x2048 bf16 = 32MB
  ushort* Wqb = (ushort*)(ws + 33554432);       // 8MB each
  ushort* Wkb = (ushort*)(ws + 41943040);
  ushort* Wvb = (ushort*)(ws + 50331648);
  ushort* Wpb = (ushort*)(ws + 58720256);
  ushort* Qb  = (ushort*)(ws + 67108864);       // (bh,t,d) 32MB
  ushort* Kb  = (ushort*)(ws + 100663296);      // (bh,t,d) 32MB
  ushort* Vtb = (ushort*)(ws + 134217728);      // (bh,d,t) 32MB
  ushort* Yb  = (ushort*)(ws + 167772160);      // (b*t, C) 32MB

  cast_bf16_kernel<<<16384, 256, 0, stream>>>(x,  xb,  4194304);
  cast_bf16_kernel<<<4096,  256, 0, stream>>>(Wq, Wqb, 1048576);
  cast_bf16_kernel<<<4096,  256, 0, stream>>>(Wk, Wkb, 1048576);
  cast_bf16_kernel<<<4096,  256, 0, stream>>>(Wv, Wvb, 1048576);
  cast_bf16_kernel<<<4096,  256, 0, stream>>>(Wp, Wpb, 1048576);

  dim3 gg(64, 16), gb(256);
  gemm_bt<<<gg, gb, 0, stream>>>(xb, Wqb, bq, Qb,  0, 8192, 2048, 2048);
  gemm_bt<<<gg, gb, 0, stream>>>(xb, Wkb, bk, Kb,  0, 8192, 2048, 2048);
  gemm_bt<<<gg, gb, 0, stream>>>(xb, Wvb, bv, Vtb, 1, 8192, 2048, 2048);

  attn_kernel<<<dim3(16, 64), 256, 0, stream>>>(Qb, Kb, Vtb, amask, Yb);

  gemm_bt<<<gg, gb, 0, stream>>>(Yb, Wpb, bp, d_out, 2, 8192, 2048, 2048);
}

// Round 2
// 886.854 us; speedup vs baseline: 5.4638x; 5.4638x over previous
//
#include <hip/hip_runtime.h>
#include <hip/hip_bf16.h>

#define G1 __attribute__((address_space(1)))
#define L3 __attribute__((address_space(3)))

typedef __bf16 bf16x8 __attribute__((ext_vector_type(8)));
typedef float f32x4 __attribute__((ext_vector_type(4)));

__device__ __forceinline__ ushort f2bf(float f) {
  union { float f; uint u; } v; v.f = f;
  uint u = v.u;
  u += 0x7fffu + ((u >> 16) & 1u);   // RNE
  return (ushort)(u >> 16);
}

// ---------------- cast fp32 -> bf16 ----------------
__global__ void cast_bf16_kernel(const float* __restrict__ in, ushort* __restrict__ out, int n4) {
  int i = blockIdx.x * 256 + threadIdx.x;
  if (i >= n4) return;
  float4 v = ((const float4*)in)[i];
  ushort4 o;
  o.x = f2bf(v.x); o.y = f2bf(v.y); o.z = f2bf(v.z); o.w = f2bf(v.w);
  ((ushort4*)out)[i] = o;
}

// ---------------- bt-GEMM: out[m][n] = sum_k A[m][k]*B[n][k] + bias[n] ----------------
// MODE 0: out bf16 at [(b*16+h)*2048+t][dd]  (Q/K layout, m=b*2048+t, n=h*128+dd)
// MODE 1: out bf16 at [(b*16+h)*128+dd][t]   (V transposed)
// MODE 2: out fp32 row-major [m][n]
template <int MODE>
__global__ __launch_bounds__(256, 2)
void gemm_bt(const ushort* __restrict__ A, const ushort* __restrict__ Bm,
             const float* __restrict__ bias, void* __restrict__ outp,
             int M, int N, int K) {
  __shared__ ushort As[128 * 32];
  __shared__ ushort Bs[128 * 32];
  const int tid  = threadIdx.x;
  const int wave = tid >> 6, lane = tid & 63;
  const int l15  = lane & 15, quad = lane >> 4;
  const int m0 = blockIdx.x * 128, n0 = blockIdx.y * 128;
  const int wm = (wave & 1) * 64, wn = (wave >> 1) * 64;

  f32x4 acc[4][4] = {};
  for (int k0 = 0; k0 < K; k0 += 32) {
    __syncthreads();
#pragma unroll
    for (int i = 0; i < 2; ++i) {
      int c = (wave * 2 + i) * 64 + lane;     // 16B chunk id, 0..511
      int row = c >> 2, cib = c & 3;
      const ushort* ga = A  + (size_t)(m0 + row) * K + k0 + cib * 8;
      const ushort* gb = Bm + (size_t)(n0 + row) * K + k0 + cib * 8;
      __builtin_amdgcn_global_load_lds((G1 uint*)ga, (L3 uint*)&As[c * 8], 16, 0, 0);
      __builtin_amdgcn_global_load_lds((G1 uint*)gb, (L3 uint*)&Bs[c * 8], 16, 0, 0);
    }
    __syncthreads();
    bf16x8 af[4], bfr[4];
#pragma unroll
    for (int mi = 0; mi < 4; ++mi)
      af[mi]  = *(const bf16x8*)&As[(wm + mi * 16 + l15) * 32 + quad * 8];
#pragma unroll
    for (int ni = 0; ni < 4; ++ni)
      bfr[ni] = *(const bf16x8*)&Bs[(wn + ni * 16 + l15) * 32 + quad * 8];
#pragma unroll
    for (int ni = 0; ni < 4; ++ni)
#pragma unroll
      for (int mi = 0; mi < 4; ++mi)
        acc[mi][ni] = __builtin_amdgcn_mfma_f32_16x16x32_bf16(af[mi], bfr[ni], acc[mi][ni], 0, 0, 0);
  }

#pragma unroll
  for (int mi = 0; mi < 4; ++mi)
#pragma unroll
    for (int ni = 0; ni < 4; ++ni) {
      int n = n0 + wn + ni * 16 + l15;
      float bv = bias[n];
#pragma unroll
      for (int r = 0; r < 4; ++r) {
        int m = m0 + wm + mi * 16 + quad * 4 + r;   // C/D: row = quad*4+reg, col = l15 (m89/m91)
        float v = acc[mi][ni][r] + bv;
        if (MODE == 0) {
          int b = m >> 11, t = m & 2047, h = n >> 7, dd = n & 127;
          ((ushort*)outp)[(((size_t)(b * 16 + h) * 2048 + t) << 7) + dd] = f2bf(v);
        } else if (MODE == 1) {
          int b = m >> 11, t = m & 2047, h = n >> 7, dd = n & 127;
          ((ushort*)outp)[(((size_t)(b * 16 + h) * 128 + dd) << 11) + t] = f2bf(v);
        } else {
          ((float*)outp)[(size_t)m * N + n] = v;
        }
      }
    }
}

// ---------------- flash attention: Q,K (bh,t,d) bf16; Vt (bh,d,t) bf16; Y (b,t,C) bf16 ----------------
__global__ __launch_bounds__(256, 2)
void attn_kernel(const ushort* __restrict__ Q, const ushort* __restrict__ Kh,
                 const ushort* __restrict__ Vt, const float* __restrict__ mask,
                 ushort* __restrict__ Y) {
  __shared__ ushort Ks[64 * 128];    // K-tile, rows=t (64), cols=d (128), no pad (global_load_lds)
  __shared__ ushort Vs[128 * 72];    // Vt-tile, rows=d (128), cols=t (64), stride 72 (16B-aligned pad)
  __shared__ ushort Ps[4 * 32 * 64]; // per-wave P (32 q-rows x 64 k-cols)
  const int tid  = threadIdx.x;
  const int wave = tid >> 6, lane = tid & 63;
  const int l15  = lane & 15, quad = lane >> 4;
  const int qt = blockIdx.x, bh = blockIdx.y;
  const int b  = bh >> 4;
  const int qw0 = qt * 128 + wave * 32;
  const ushort* Qb = Q  + (size_t)bh * 2048 * 128;
  const ushort* Kb = Kh + (size_t)bh * 2048 * 128;
  const ushort* Vb = Vt + (size_t)bh * 128 * 2048;
  const float*  mrow = mask + b * 2048;

  bf16x8 aq[2][4];   // Q A-frags: A[m=l15][k=quad*8+j], dk covers d=128
#pragma unroll
  for (int m2 = 0; m2 < 2; ++m2)
#pragma unroll
    for (int dk = 0; dk < 4; ++dk)
      aq[m2][dk] = *(const bf16x8*)(Qb + (size_t)(qw0 + m2 * 16 + l15) * 128 + dk * 32 + quad * 8);

  float mi_[2][4], li[2][4];
  f32x4 O[2][8] = {};
#pragma unroll
  for (int m2 = 0; m2 < 2; ++m2)
#pragma unroll
    for (int r = 0; r < 4; ++r) { mi_[m2][r] = -3.0e38f; li[m2][r] = 0.f; }

  const float scale = 0.08838834764831845f;  // 1/sqrt(128)
  const int nkt = 2 * qt + 2;
  for (int it = 0; it < nkt; ++it) {
    const int k0 = it * 64;
    __syncthreads();
    // stage K tile: 16KB globally contiguous
#pragma unroll
    for (int i = 0; i < 4; ++i) {
      int c = (wave * 4 + i) * 64 + lane;
      __builtin_amdgcn_global_load_lds((G1 uint*)(Kb + (size_t)k0 * 128 + c * 8),
                                       (L3 uint*)&Ks[c * 8], 16, 0, 0);
    }
    // stage Vt tile via VGPRs (padded LDS rows)
    uint4 vv[4]; int dvi[4], cki[4];
#pragma unroll
    for (int i = 0; i < 4; ++i) {
      int idx = i * 256 + tid;
      int d = idx >> 3, ck = idx & 7;
      vv[i] = *(const uint4*)(Vb + (size_t)d * 2048 + k0 + ck * 8);
      dvi[i] = d; cki[i] = ck;
    }
#pragma unroll
    for (int i = 0; i < 4; ++i)
      *(uint4*)&Vs[dvi[i] * 72 + cki[i] * 8] = vv[i];
    __syncthreads();

    if (k0 <= qw0 + 31) {    // tile intersects this wave's causal range
      float mk[4];
#pragma unroll
      for (int ns = 0; ns < 4; ++ns) mk[ns] = mrow[k0 + ns * 16 + l15];

      f32x4 s[2][4] = {};
#pragma unroll
      for (int ns = 0; ns < 4; ++ns) {
        bf16x8 kb[4];
#pragma unroll
        for (int dk = 0; dk < 4; ++dk)
          kb[dk] = *(const bf16x8*)&Ks[(ns * 16 + l15) * 128 + dk * 32 + quad * 8];
#pragma unroll
        for (int m2 = 0; m2 < 2; ++m2)
#pragma unroll
          for (int dk = 0; dk < 4; ++dk)
            s[m2][ns] = __builtin_amdgcn_mfma_f32_16x16x32_bf16(aq[m2][dk], kb[dk], s[m2][ns], 0, 0, 0);
      }

#pragma unroll
      for (int m2 = 0; m2 < 2; ++m2) {
#pragma unroll
        for (int ns = 0; ns < 4; ++ns) {
          int kc = k0 + ns * 16 + l15;
#pragma unroll
          for (int r = 0; r < 4; ++r) {
            int qr = qw0 + m2 * 16 + quad * 4 + r;
            float v = s[m2][ns][r] * scale + mk[ns];
            s[m2][ns][r] = (kc > qr) ? -3.0e38f : v;
          }
        }
#pragma unroll
        for (int r = 0; r < 4; ++r) {
          float rm = fmaxf(fmaxf(s[m2][0][r], s[m2][1][r]), fmaxf(s[m2][2][r], s[m2][3][r]));
          rm = fmaxf(rm, __shfl_xor(rm, 1));
          rm = fmaxf(rm, __shfl_xor(rm, 2));
          rm = fmaxf(rm, __shfl_xor(rm, 4));
          rm = fmaxf(rm, __shfl_xor(rm, 8));
          float mold = mi_[m2][r];
          float mnew = fmaxf(mold, rm);
          float al = __expf(mold - mnew);
          float rs = 0.f;
#pragma unroll
          for (int ns = 0; ns < 4; ++ns) {
            float p = __expf(s[m2][ns][r] - mnew);
            rs += p;
            Ps[wave * 2048 + (m2 * 16 + quad * 4 + r) * 64 + ns * 16 + l15] = f2bf(p);
          }
          rs += __shfl_xor(rs, 1);
          rs += __shfl_xor(rs, 2);
          rs += __shfl_xor(rs, 4);
          rs += __shfl_xor(rs, 8);
          li[m2][r] = li[m2][r] * al + rs;
          mi_[m2][r] = mnew;
#pragma unroll
          for (int dd = 0; dd < 8; ++dd) O[m2][dd][r] *= al;
        }
      }
      // PV: P (A-layout from LDS) x Vt (B[k][n] = Vs[n][k], contiguous along k)
#pragma unroll
      for (int kk = 0; kk < 2; ++kk) {
        bf16x8 pa[2];
#pragma unroll
        for (int m2 = 0; m2 < 2; ++m2)
          pa[m2] = *(const bf16x8*)&Ps[wave * 2048 + (m2 * 16 + l15) * 64 + kk * 32 + quad * 8];
#pragma unroll
        for (int dd = 0; dd < 8; ++dd) {
          bf16x8 vbf = *(const bf16x8*)&Vs[(dd * 16 + l15) * 72 + kk * 32 + quad * 8];
#pragma unroll
          for (int m2 = 0; m2 < 2; ++m2)
            O[m2][dd] = __builtin_amdgcn_mfma_f32_16x16x32_bf16(pa[m2], vbf, O[m2][dd], 0, 0, 0);
        }
      }
    }
  }

#pragma unroll
  for (int m2 = 0; m2 < 2; ++m2)
#pragma unroll
    for (int dd = 0; dd < 8; ++dd)
#pragma unroll
      for (int r = 0; r < 4; ++r) {
        float v = O[m2][dd][r] / li[m2][r];
        int t = qw0 + m2 * 16 + quad * 4 + r;
        Y[((size_t)(b * 2048 + t)) * 2048 + (bh & 15) * 128 + dd * 16 + l15] = f2bf(v);
      }
}

extern "C" void kernel_launch(void* const* d_in, const int* in_sizes, int n_in,
                              void* d_out, int out_size, void* d_ws, size_t ws_size,
                              hipStream_t stream) {
  const float* x     = (const float*)d_in[0];
  const float* amask = (const float*)d_in[1];
  const float* Wq = (const float*)d_in[2];
  const float* bq = (const float*)d_in[3];
  const float* Wk = (const float*)d_in[4];
  const float* bk = (const float*)d_in[5];
  const float* Wv = (const float*)d_in[6];
  const float* bv = (const float*)d_in[7];
  const float* Wp = (const float*)d_in[8];
  const float* bp = (const float*)d_in[9];

  char* ws = (char*)d_ws;
  ushort* xb  = (ushort*)(ws);                  // 8192x2048 bf16 = 32MB
  ushort* Wqb = (ushort*)(ws + 33554432);       // 8MB each
  ushort* Wkb = (ushort*)(ws + 41943040);
  ushort* Wvb = (ushort*)(ws + 50331648);
  ushort* Wpb = (ushort*)(ws + 58720256);
  ushort* Qb  = (ushort*)(ws + 67108864);       // (bh,t,d) 32MB
  ushort* Kb  = (ushort*)(ws + 100663296);      // (bh,t,d) 32MB
  ushort* Vtb = (ushort*)(ws + 134217728);      // (bh,d,t) 32MB
  ushort* Yb  = (ushort*)(ws + 167772160);      // (b*t, C) 32MB

  cast_bf16_kernel<<<16384, 256, 0, stream>>>(x,  xb,  4194304);
  cast_bf16_kernel<<<4096,  256, 0, stream>>>(Wq, Wqb, 1048576);
  cast_bf16_kernel<<<4096,  256, 0, stream>>>(Wk, Wkb, 1048576);
  cast_bf16_kernel<<<4096,  256, 0, stream>>>(Wv, Wvb, 1048576);
  cast_bf16_kernel<<<4096,  256, 0, stream>>>(Wp, Wpb, 1048576);

  dim3 gg(64, 16), gb(256);
  gemm_bt<0><<<gg, gb, 0, stream>>>(xb, Wqb, bq, Qb,  8192, 2048, 2048);
  gemm_bt<0><<<gg, gb, 0, stream>>>(xb, Wkb, bk, Kb,  8192, 2048, 2048);
  gemm_bt<1><<<gg, gb, 0, stream>>>(xb, Wvb, bv, Vtb, 8192, 2048, 2048);

  attn_kernel<<<dim3(16, 64), 256, 0, stream>>>(Qb, Kb, Vtb, amask, Yb);

  gemm_bt<2><<<gg, gb, 0, stream>>>(Yb, Wpb, bp, d_out, 8192, 2048, 2048);
}

// Round 3
// 688.655 us; speedup vs baseline: 7.0364x; 1.2878x over previous
//
#include <hip/hip_runtime.h>
#include <hip/hip_bf16.h>

#define G1 __attribute__((address_space(1)))
#define L3 __attribute__((address_space(3)))

typedef __bf16 bf16x8 __attribute__((ext_vector_type(8)));
typedef _Float16 half4 __attribute__((ext_vector_type(4)));
typedef float f32x4 __attribute__((ext_vector_type(4)));

__device__ __forceinline__ ushort f2bf(float f) {
  union { float f; uint u; } v; v.f = f;
  uint u = v.u;
  u += 0x7fffu + ((u >> 16) & 1u);   // RNE
  return (ushort)(u >> 16);
}
__device__ __forceinline__ ushort f2h(float f) {
  _Float16 h = (_Float16)f;
  union { _Float16 h; ushort u; } v; v.h = h;
  return v.u;
}

// ---------------- cast fp32 -> bf16 ----------------
__global__ void cast_bf16_kernel(const float* __restrict__ in, ushort* __restrict__ out, int n4) {
  int i = blockIdx.x * 256 + threadIdx.x;
  if (i >= n4) return;
  float4 v = ((const float4*)in)[i];
  ushort4 o;
  o.x = f2bf(v.x); o.y = f2bf(v.y); o.z = f2bf(v.z); o.w = f2bf(v.w);
  ((ushort4*)out)[i] = o;
}

// ---------------- bt-GEMM: out[m][n] = sum_k A[m][k]*B[n][k] + bias[n] ----------------
// MODE 0: out bf16 at [(b*16+h)*2048+t][dd]  (Q/K layout, m=b*2048+t, n=h*128+dd)
// MODE 1: out fp16 at [(b*16+h)*128+dd][t]   (V transposed, fp16 for PV mfma)
// MODE 2: out fp32 row-major [m][n]
template <int MODE>
__global__ __launch_bounds__(256, 2)
void gemm_bt(const ushort* __restrict__ A, const ushort* __restrict__ Bm,
             const float* __restrict__ bias, void* __restrict__ outp,
             int M, int N, int K) {
  __shared__ ushort As[128 * 32];
  __shared__ ushort Bs[128 * 32];
  const int tid  = threadIdx.x;
  const int wave = tid >> 6, lane = tid & 63;
  const int l15  = lane & 15, quad = lane >> 4;
  const int m0 = blockIdx.x * 128, n0 = blockIdx.y * 128;
  const int wm = (wave & 1) * 64, wn = (wave >> 1) * 64;

  f32x4 acc[4][4] = {};
  for (int k0 = 0; k0 < K; k0 += 32) {
    __syncthreads();
#pragma unroll
    for (int i = 0; i < 2; ++i) {
      int c = (wave * 2 + i) * 64 + lane;     // 16B chunk id, 0..511
      int row = c >> 2, cib = c & 3;
      const ushort* ga = A  + (size_t)(m0 + row) * K + k0 + cib * 8;
      const ushort* gb = Bm + (size_t)(n0 + row) * K + k0 + cib * 8;
      __builtin_amdgcn_global_load_lds((G1 uint*)ga, (L3 uint*)&As[c * 8], 16, 0, 0);
      __builtin_amdgcn_global_load_lds((G1 uint*)gb, (L3 uint*)&Bs[c * 8], 16, 0, 0);
    }
    __syncthreads();
    bf16x8 af[4], bfr[4];
#pragma unroll
    for (int mi = 0; mi < 4; ++mi)
      af[mi]  = *(const bf16x8*)&As[(wm + mi * 16 + l15) * 32 + quad * 8];
#pragma unroll
    for (int ni = 0; ni < 4; ++ni)
      bfr[ni] = *(const bf16x8*)&Bs[(wn + ni * 16 + l15) * 32 + quad * 8];
#pragma unroll
    for (int ni = 0; ni < 4; ++ni)
#pragma unroll
      for (int mi = 0; mi < 4; ++mi)
        acc[mi][ni] = __builtin_amdgcn_mfma_f32_16x16x32_bf16(af[mi], bfr[ni], acc[mi][ni], 0, 0, 0);
  }

#pragma unroll
  for (int mi = 0; mi < 4; ++mi)
#pragma unroll
    for (int ni = 0; ni < 4; ++ni) {
      int n = n0 + wn + ni * 16 + l15;
      float bv = bias[n];
#pragma unroll
      for (int r = 0; r < 4; ++r) {
        int m = m0 + wm + mi * 16 + quad * 4 + r;   // C/D: row = quad*4+reg, col = l15 (m89/m91)
        float v = acc[mi][ni][r] + bv;
        if (MODE == 0) {
          int b = m >> 11, t = m & 2047, h = n >> 7, dd = n & 127;
          ((ushort*)outp)[(((size_t)(b * 16 + h) * 2048 + t) << 7) + dd] = f2bf(v);
        } else if (MODE == 1) {
          int b = m >> 11, t = m & 2047, h = n >> 7, dd = n & 127;
          ((ushort*)outp)[(((size_t)(b * 16 + h) * 128 + dd) << 11) + t] = f2h(v);
        } else {
          ((float*)outp)[(size_t)m * N + n] = v;
        }
      }
    }
}

// ---------------- flash attention (S^T form) ----------------
// Q,K: (bh,t,d) bf16.  Vt: (bh,d,t) fp16.  Y: (b,t,C) bf16.
// S^T = K.Q^T via 16x16x32 bf16 (A=K, B=Q): C-layout lane=qr(l15), reg=kc(quad*4+r)
// -> directly the B-frag of 16x16x16 f16 PV (no LDS round-trip for P).
// O kept transposed (OT[dd][qr]) so per-row softmax state is lane-uniform.
__global__ __launch_bounds__(256, 3)
void attn_kernel(const ushort* __restrict__ Q, const ushort* __restrict__ Kh,
                 const ushort* __restrict__ Vt, const float* __restrict__ mask,
                 ushort* __restrict__ Y) {
  __shared__ ushort Ks[64 * 128];   // XOR-swizzled: chunk(t,ck) at t*16 + (ck^ (t&15))
  __shared__ ushort Vs[128 * 64];   // XOR-swizzled: chunk(d,ck) at d*8  + (ck^ (d&7))
  const int tid  = threadIdx.x;
  const int wave = tid >> 6, lane = tid & 63;
  const int l15  = lane & 15, quad = lane >> 4;
  const int bh = blockIdx.x;                  // bh-major
  const int qt = 15 - blockIdx.y;             // longest blocks dispatch first
  const int b  = bh >> 4, h = bh & 15;
  const int qw0 = qt * 128 + wave * 32;
  const ushort* Qb = Q  + (size_t)bh * 2048 * 128;
  const ushort* Kb = Kh + (size_t)bh * 2048 * 128;
  const ushort* Vb = Vt + (size_t)bh * 128 * 2048;
  const float*  mrow = mask + b * 2048;

  // Q B-frags (persistent): lane l15 = qr, k=d = dk*32+quad*8..+7
  bf16x8 aq[2][4];
#pragma unroll
  for (int q2 = 0; q2 < 2; ++q2)
#pragma unroll
    for (int dk = 0; dk < 4; ++dk)
      aq[q2][dk] = *(const bf16x8*)(Qb + (size_t)(qw0 + q2 * 16 + l15) * 128 + dk * 32 + quad * 8);

  float mi_[2], li[2];
  f32x4 OT[8][2] = {};   // OT[ddt][q2]: rows dd=ddt*16+quad*4+r, cols qr=q2*16+l15
  mi_[0] = mi_[1] = -3.0e38f;
  li[0] = li[1] = 0.f;

  const float scale = 0.08838834764831845f;  // 1/sqrt(128)
  const int nkt = 2 * qt + 2;
  for (int it = 0; it < nkt; ++it) {
    const int k0 = it * 64;
    __syncthreads();
    // stage K tile (64 t x 128 d, 16KB) swizzled
#pragma unroll
    for (int i = 0; i < 4; ++i) {
      int c = i * 256 + tid;                      // LDS chunk 0..1023
      int t = c >> 4, ckG = (c & 15) ^ (t & 15);  // global chunk for this LDS slot
      __builtin_amdgcn_global_load_lds((G1 uint*)(Kb + (size_t)(k0 + t) * 128 + ckG * 8),
                                       (L3 uint*)&Ks[c * 8], 16, 0, 0);
    }
    // stage V tile (128 d x 64 t, 16KB) swizzled
#pragma unroll
    for (int i = 0; i < 4; ++i) {
      int c = i * 256 + tid;
      int d = c >> 3, ckG = (c & 7) ^ (d & 7);
      __builtin_amdgcn_global_load_lds((G1 uint*)(Vb + (size_t)d * 2048 + k0 + ckG * 8),
                                       (L3 uint*)&Vs[c * 8], 16, 0, 0);
    }
    __syncthreads();

    if (k0 <= qw0 + 31) {    // tile intersects this wave's causal range
      float4 mk[4];
#pragma unroll
      for (int ns = 0; ns < 4; ++ns)
        mk[ns] = *(const float4*)&mrow[k0 + ns * 16 + quad * 4];

      // S^T: A = K (lane l15 = kc-row), B = Q
      f32x4 s[2][4] = {};
#pragma unroll
      for (int ns = 0; ns < 4; ++ns) {
        bf16x8 kb[4];
#pragma unroll
        for (int dk = 0; dk < 4; ++dk) {
          int ck = ((dk * 4 + quad) ^ l15);   // swizzled chunk
          kb[dk] = *(const bf16x8*)&Ks[(ns * 16 + l15) * 128 + ck * 8];
        }
#pragma unroll
        for (int q2 = 0; q2 < 2; ++q2)
#pragma unroll
          for (int dk = 0; dk < 4; ++dk)
            s[q2][ns] = __builtin_amdgcn_mfma_f32_16x16x32_bf16(kb[dk], aq[q2][dk], s[q2][ns], 0, 0, 0);
      }

      // scale + additive mask + causal (element: kc = k0+16ns+quad*4+r, qr = qw0+q2*16+l15)
      half4 pf[2][4];
#pragma unroll
      for (int q2 = 0; q2 < 2; ++q2) {
        const int qr = qw0 + q2 * 16 + l15;
#pragma unroll
        for (int ns = 0; ns < 4; ++ns)
#pragma unroll
          for (int r = 0; r < 4; ++r) {
            int kc = k0 + ns * 16 + quad * 4 + r;
            float v = s[q2][ns][r] * scale + mk[ns][r];
            s[q2][ns][r] = (kc > qr) ? -3.0e38f : v;
          }
        // row softmax: state lives in every lane (4 quad-copies, identical)
        float rm = -3.0e38f;
#pragma unroll
        for (int ns = 0; ns < 4; ++ns)
          rm = fmaxf(rm, fmaxf(fmaxf(s[q2][ns][0], s[q2][ns][1]), fmaxf(s[q2][ns][2], s[q2][ns][3])));
        rm = fmaxf(rm, __shfl_xor(rm, 16));
        rm = fmaxf(rm, __shfl_xor(rm, 32));
        float mnew = fmaxf(mi_[q2], rm);
        float al = __expf(mi_[q2] - mnew);
        float rs = 0.f;
#pragma unroll
        for (int ns = 0; ns < 4; ++ns) {
#pragma unroll
          for (int r = 0; r < 4; ++r) {
            float p = __expf(s[q2][ns][r] - mnew);
            s[q2][ns][r] = p;
            rs += p;
          }
          pf[q2][ns] = half4{(_Float16)s[q2][ns][0], (_Float16)s[q2][ns][1],
                             (_Float16)s[q2][ns][2], (_Float16)s[q2][ns][3]};
        }
        rs += __shfl_xor(rs, 16);
        rs += __shfl_xor(rs, 32);
        li[q2] = li[q2] * al + rs;
        mi_[q2] = mnew;
#pragma unroll
        for (int ddt = 0; ddt < 8; ++ddt) OT[ddt][q2] *= al;
      }

      // PV: OT[ddt][q2] += mfma_16x16x16_f16(A=V^T frag, B=P frag)
#pragma unroll
      for (int ns = 0; ns < 4; ++ns)
#pragma unroll
        for (int ddt = 0; ddt < 8; ++ddt) {
          int row = ddt * 16 + l15;
          int ck = (2 * ns + (quad >> 1)) ^ (l15 & 7);   // swizzled 16B chunk
          half4 vf = *(const half4*)&Vs[row * 64 + ck * 8 + (quad & 1) * 4];
#pragma unroll
          for (int q2 = 0; q2 < 2; ++q2)
            OT[ddt][q2] = __builtin_amdgcn_mfma_f32_16x16x16f16(vf, pf[q2][ns], OT[ddt][q2], 0, 0, 0);
        }
    }
  }

  // epilogue: O[qr][dd] = OT[dd][qr] / li ; write 8B per (ddt,q2) per lane
#pragma unroll
  for (int q2 = 0; q2 < 2; ++q2) {
    float inv = 1.0f / li[q2];
    int t = qw0 + q2 * 16 + l15;
#pragma unroll
    for (int ddt = 0; ddt < 8; ++ddt) {
      ushort4 o;
      o.x = f2bf(OT[ddt][q2][0] * inv);
      o.y = f2bf(OT[ddt][q2][1] * inv);
      o.z = f2bf(OT[ddt][q2][2] * inv);
      o.w = f2bf(OT[ddt][q2][3] * inv);
      *(ushort4*)&Y[((size_t)(b * 2048 + t)) * 2048 + h * 128 + ddt * 16 + quad * 4] = o;
    }
  }
}

extern "C" void kernel_launch(void* const* d_in, const int* in_sizes, int n_in,
                              void* d_out, int out_size, void* d_ws, size_t ws_size,
                              hipStream_t stream) {
  const float* x     = (const float*)d_in[0];
  const float* amask = (const float*)d_in[1];
  const float* Wq = (const float*)d_in[2];
  const float* bq = (const float*)d_in[3];
  const float* Wk = (const float*)d_in[4];
  const float* bk = (const float*)d_in[5];
  const float* Wv = (const float*)d_in[6];
  const float* bv = (const float*)d_in[7];
  const float* Wp = (const float*)d_in[8];
  const float* bp = (const float*)d_in[9];

  char* ws = (char*)d_ws;
  ushort* xb  = (ushort*)(ws);                  // 8192x2048 bf16 = 32MB
  ushort* Wqb = (ushort*)(ws + 33554432);       // 8MB each
  ushort* Wkb = (ushort*)(ws + 41943040);
  ushort* Wvb = (ushort*)(ws + 50331648);
  ushort* Wpb = (ushort*)(ws + 58720256);
  ushort* Qb  = (ushort*)(ws + 67108864);       // (bh,t,d) bf16 32MB
  ushort* Kb  = (ushort*)(ws + 100663296);      // (bh,t,d) bf16 32MB
  ushort* Vtb = (ushort*)(ws + 134217728);      // (bh,d,t) fp16 32MB
  ushort* Yb  = (ushort*)(ws + 167772160);      // (b*t, C) bf16 32MB

  cast_bf16_kernel<<<16384, 256, 0, stream>>>(x,  xb,  4194304);
  cast_bf16_kernel<<<4096,  256, 0, stream>>>(Wq, Wqb, 1048576);
  cast_bf16_kernel<<<4096,  256, 0, stream>>>(Wk, Wkb, 1048576);
  cast_bf16_kernel<<<4096,  256, 0, stream>>>(Wv, Wvb, 1048576);
  cast_bf16_kernel<<<4096,  256, 0, stream>>>(Wp, Wpb, 1048576);

  dim3 gg(64, 16), gb(256);
  gemm_bt<0><<<gg, gb, 0, stream>>>(xb, Wqb, bq, Qb,  8192, 2048, 2048);
  gemm_bt<0><<<gg, gb, 0, stream>>>(xb, Wkb, bk, Kb,  8192, 2048, 2048);
  gemm_bt<1><<<gg, gb, 0, stream>>>(xb, Wvb, bv, Vtb, 8192, 2048, 2048);

  attn_kernel<<<dim3(64, 16), 256, 0, stream>>>(Qb, Kb, Vtb, amask, Yb);

  gemm_bt<2><<<gg, gb, 0, stream>>>(Yb, Wpb, bp, d_out, 8192, 2048, 2048);
}